// Round 9
// baseline (299.504 us; speedup 1.0000x reference)
//
#include <hip/hip_runtime.h>

#define H 224
#define W 224
#define HW (H*W)
#define BATCH 2
#define CIN 64
#define COUT 64
#define NOFF 18
#define K576 576          // K = 64 ch * 9 taps
#define OFFS 20           // off LDS stride (18 live, f4-aligned)
#define NBLK (BATCH*HW/64)          // 1568 tiles (8x8 pixels)
#define NB8  (NBLK/8)               // 196 blocks per XCD span
#define TC8  28                     // 224/8 tiles per image row/col
#define XROW 68                     // staged patch ch-stride (64 + 4 pad)
#define PRW 10                      // patch rows (8 + 2 halo)
#define PCW 10                      // patch cols
#define LDROW 72                    // epilogue staging stride
#define TPB  (BATCH*HW/64)          // transpose blocks = 1568

typedef __attribute__((ext_vector_type(8))) short bf16x8;
typedef __attribute__((ext_vector_type(4))) short s16x4;
typedef __attribute__((ext_vector_type(4))) float f32x4;

__device__ inline short f2bf(float f) {
    unsigned u = __float_as_uint(f);
    u += 0x7FFF + ((u >> 16) & 1);
    return (short)(u >> 16);
}
__device__ inline float bf2f(short h) {
    return __uint_as_float(((unsigned)(unsigned short)h) << 16);
}
__device__ inline void split_bf(float x, short& hi, short& lo) {
    hi = f2bf(x);
    lo = f2bf(x - bf2f(hi));
}
__device__ inline void split_bf4(float a, float b, float c, float d,
                                 s16x4& h4, s16x4& l4) {
    short h0, l0, h1, l1, h2, l2, h3, l3;
    split_bf(a, h0, l0); split_bf(b, h1, l1);
    split_bf(c, h2, l2); split_bf(d, h3, l3);
    h4 = (s16x4){h0, h1, h2, h3};
    l4 = (s16x4){l0, l1, l2, l3};
}
__device__ inline void split_bf8(float a0, float a1, float a2, float a3,
                                 float a4, float a5, float a6, float a7,
                                 bf16x8& hi, bf16x8& lo) {
    s16x4 h0, l0, h1, l1;
    split_bf4(a0, a1, a2, a3, h0, l0);
    split_bf4(a4, a5, a6, a7, h1, l1);
    hi = __builtin_shufflevector(h0, h1, 0, 1, 2, 3, 4, 5, 6, 7);
    lo = __builtin_shufflevector(l0, l1, 0, 1, 2, 3, 4, 5, 6, 7);
}
__device__ inline bf16x8 cvt8hi(const float* s) {
    return (bf16x8){f2bf(s[0]), f2bf(s[1]), f2bf(s[2]), f2bf(s[3]),
                    f2bf(s[4]), f2bf(s[5]), f2bf(s[6]), f2bf(s[7])};
}
__device__ inline int swizzle_blk(int raw) {
    return (raw & 7) * NB8 + (raw >> 3);
}
__device__ __forceinline__ float f4get(float4 v, int k) {
    switch (k & 3) { case 0: return v.x; case 1: return v.y; case 2: return v.z; default: return v.w; }
}
// BN scale/shift for channel c from atomically-accumulated (sum, sumsq).
__device__ __forceinline__ void bn_coef(const float* acc, const float* gamma,
                                        const float* beta, int c,
                                        float& scale, float& shift) {
    const float inv_m = 1.0f / (float)(BATCH * HW);
    float mu  = acc[c] * inv_m;
    float var = acc[64 + c] * inv_m - mu * mu;
    scale = rsqrtf(var + 1e-5f) * gamma[c];
    shift = beta[c] - mu * scale;
}

// ---------------------------------------------------------------------------
// Combined front kernel: blocks [0,TPB) transpose x NCHW->NHWC; blocks
// [TPB, TPB+216) prep BOTH stages' weights (wave-contiguous fragment layout):
// Deform:  Wd[((chunk*9+kt)*4+nt)*512 + lane*8 + e]
//   n = nt*16 + (lane&15); c = chunk*32 + (lane>>4)*8 + e; tap = kt
// Offconv: Wo[((chunk*9+kt)*2+ntb)*512 + lane*8 + e]   (n>=18 rows zero)
// ---------------------------------------------------------------------------
__global__ __launch_bounds__(256) void k_prep_all(const float* __restrict__ x,
                                                  float* __restrict__ xT,
                                                  const float* __restrict__ wconv1,
                                                  const float* __restrict__ woff1,
                                                  const float* __restrict__ wconv2,
                                                  const float* __restrict__ woff2,
                                                  short* __restrict__ Wtd1h,
                                                  short* __restrict__ Wtd1l,
                                                  short* __restrict__ Wto1h,
                                                  short* __restrict__ Wto1l,
                                                  short* __restrict__ Wtd2h,
                                                  short* __restrict__ Wtd2l,
                                                  short* __restrict__ Wto2h,
                                                  short* __restrict__ Wto2l) {
    __shared__ float Lt[64][65];
    if (blockIdx.x < TPB) {
        // ---- NCHW -> NHWC transpose (identical to R1 k_transpose) ----
        int blk = blockIdx.x, t = threadIdx.x;
        int px0 = blk * 64;
        int b   = px0 / HW;
        int ij0 = px0 - b * HW;
        int lane = t & 63, g = t >> 6;
#pragma unroll
        for (int r = 0; r < 16; ++r) {
            int c = r * 4 + g;
            Lt[c][lane] = x[(b * CIN + c) * HW + ij0 + lane];
        }
        __syncthreads();
#pragma unroll
        for (int r = 0; r < 16; ++r) {
            int px = r * 4 + g;
            xT[((size_t)(b * HW + ij0 + px)) * 64 + lane] = Lt[lane][px];
        }
        return;
    }
    // ---- weight prep, both stages ----
    int t = (blockIdx.x - TPB) * 256 + threadIdx.x;
    if (t < COUT * K576) {
        int e = t & 7, lane = (t >> 3) & 63, rest = t >> 9;
        int nt = rest & 3, kt9 = rest >> 2;
        int kt = kt9 % 9, chunk = kt9 / 9;
        int n = nt * 16 + (lane & 15);
        int c = chunk * 32 + (lane >> 4) * 8 + e;
        short h, l;
        split_bf(wconv1[n * K576 + c * 9 + kt], h, l);
        Wtd1h[t] = h; Wtd1l[t] = l;
        split_bf(wconv2[n * K576 + c * 9 + kt], h, l);
        Wtd2h[t] = h; Wtd2l[t] = l;
    }
    int t2 = t - COUT * K576;
    if (t2 >= 0 && t2 < 32 * K576) {
        int e = t2 & 7, lane = (t2 >> 3) & 63, rest = t2 >> 9;
        int ntb = rest & 1, kt9 = rest >> 1;
        int kt = kt9 % 9, chunk = kt9 / 9;
        int n = ntb * 16 + (lane & 15);
        int c = chunk * 32 + (lane >> 4) * 8 + e;
        short h, l;
        float v1 = (n < NOFF) ? woff1[n * K576 + c * 9 + kt] : 0.0f;
        split_bf(v1, h, l);
        Wto1h[t2] = h; Wto1l[t2] = l;
        float v2 = (n < NOFF) ? woff2[n * K576 + c * 9 + kt] : 0.0f;
        split_bf(v2, h, l);
        Wto2h[t2] = h; Wto2l[t2] = l;
    }
}

// ---------------------------------------------------------------------------
// FUSED, wave-autonomous — R6 kernel (passed, 289 us, absmax 0.125) with ONE
// tail change: per-block (sum,sumsq) go to global atomics instead of part[].
//   LO=true  (stage 1): full 3-term hi/lo bf16 deform product (y1 feeds
//     stage-2's offset conv -> floor(); R2 post-mortem).
//   LO=false (stage 2): hi*hi only deform (feeds only BN+ReLU; error ~0.06
//     << 0.795 threshold).
// NOTE: BN-at-load fusion (BN_IN) is PERMANENTLY BANNED — failed correctness
// three times (R2 3.4, R3 2.9, R7 1.156 scalar-only) with no mechanism found;
// BN1 stays a standalone pass (k_bnrelu_nhwc).
// ---------------------------------------------------------------------------
template <bool OUT_NHWC, bool LO>
__global__ __launch_bounds__(256, 4) void k_fused(const float* __restrict__ xT,
                                                  const short* __restrict__ Wtoh,
                                                  const short* __restrict__ Wtol,
                                                  const float* __restrict__ boff,
                                                  const short* __restrict__ Wtdh,
                                                  const short* __restrict__ Wtdl,
                                                  float* __restrict__ out,
                                                  float* __restrict__ acc_g) {
    // LDS: Xs 27200 | offL 5120 = 32320 B. Ld (18432) + Sr (2048) reuse them.
    __shared__ __align__(16) char smem[PRW * PCW * XROW * 4 + 64 * OFFS * 4];
    float* Xs   = (float*)smem;
    float* offL = (float*)(smem + PRW * PCW * XROW * 4);

    const int t    = threadIdx.x;
    const int lane = t & 63;
    const int wv   = t >> 6;
    const int l15  = lane & 15;
    const int quad = lane >> 4;
    const int vb   = swizzle_blk(blockIdx.x);
    const int b    = vb / (TC8 * TC8);
    const int rem  = vb - b * (TC8 * TC8);
    const int i0   = (rem / TC8) * 8;
    const int j0   = (rem % TC8) * 8;
    const int lp   = wv * 16 + l15;          // this lane's pixel 0..63
    const int i    = i0 + (lp >> 3);
    const int j    = j0 + (lp & 7);

    const float* xb = xT + (size_t)(b * HW) * 64;

    // ---- stage 10x10x64ch patch (border-clamped), shared by both phases ----
#pragma unroll
    for (int k = 0; k < 7; ++k) {
        int idx = k * 256 + t;               // 1600 = 100 slots x 16 f4
        if (idx < PRW * PCW * 16) {
            int slot = idx >> 4, e = idx & 15;
            int sr = slot / PCW, sc = slot - sr * PCW;
            int rr = min(max(i0 - 1 + sr, 0), H - 1);
            int cc = min(max(j0 - 1 + sc, 0), W - 1);
            *(float4*)&Xs[slot * XROW + e * 4] =
                *(const float4*)(xb + (size_t)(rr * W + cc) * 64 + e * 4);
        }
    }
    __syncthreads();

    // ============ PHASE 1: offset conv (zero-pad via mask), per-wave ============
    f32x4 aoc0 = (f32x4){0.f, 0.f, 0.f, 0.f};
    f32x4 aoc1 = (f32x4){0.f, 0.f, 0.f, 0.f};
#pragma unroll
    for (int kt = 0; kt < 9; ++kt) {
        const int di = kt / 3, dj = kt % 3;
        const int ii = i + di - 1, jj = j + dj - 1;
        const bool ok = (ii >= 0) && (ii < H) && (jj >= 0) && (jj < W);
        const float* xp = &Xs[(((lp >> 3) + di) * PCW + (lp & 7) + dj) * XROW + quad * 8];
#pragma unroll
        for (int chunk = 0; chunk < 2; ++chunk) {
            float4 va = make_float4(0.f, 0.f, 0.f, 0.f), vb4 = va;
            if (ok) {
                va  = *(const float4*)(xp + chunk * 32);
                vb4 = *(const float4*)(xp + chunk * 32 + 4);
            }
            bf16x8 afh, afl;
            split_bf8(va.x, va.y, va.z, va.w, vb4.x, vb4.y, vb4.z, vb4.w, afh, afl);
            const int fb = (chunk * 9 + kt) * 2 * 512 + lane * 8;
            bf16x8 bh0 = *(const bf16x8*)(Wtoh + fb);
            bf16x8 bl0 = *(const bf16x8*)(Wtol + fb);
            aoc0 = __builtin_amdgcn_mfma_f32_16x16x32_bf16(afh, bh0, aoc0, 0, 0, 0);
            aoc0 = __builtin_amdgcn_mfma_f32_16x16x32_bf16(afl, bh0, aoc0, 0, 0, 0);
            aoc0 = __builtin_amdgcn_mfma_f32_16x16x32_bf16(afh, bl0, aoc0, 0, 0, 0);
            bf16x8 bh1 = *(const bf16x8*)(Wtoh + fb + 512);
            bf16x8 bl1 = *(const bf16x8*)(Wtol + fb + 512);
            aoc1 = __builtin_amdgcn_mfma_f32_16x16x32_bf16(afh, bh1, aoc1, 0, 0, 0);
            aoc1 = __builtin_amdgcn_mfma_f32_16x16x32_bf16(afl, bh1, aoc1, 0, 0, 0);
            aoc1 = __builtin_amdgcn_mfma_f32_16x16x32_bf16(afh, bl1, aoc1, 0, 0, 0);
        }
    }
    // redistribute offsets: C layout holds [px=quad*4+r][n=l15(+16)] -> offL
    {
        const int pr0 = wv * 16 + quad * 4;
        const float bi = boff[l15];
#pragma unroll
        for (int r = 0; r < 4; ++r)
            offL[(pr0 + r) * OFFS + l15] = aoc0[r] + bi;
        if (l15 < 2) {
            const float bi2 = boff[16 + l15];
#pragma unroll
            for (int r = 0; r < 4; ++r)
                offL[(pr0 + r) * OFFS + 16 + l15] = aoc1[r] + bi2;
        }
    }
    __syncthreads();

    // ============ PHASE 2: deformable sampling + conv, per-wave ============
    const float* ofp = &offL[(wv * 16 + l15) * OFFS];
    const float4 ofA = *(const float4*)(ofp + 0);
    const float4 ofB = *(const float4*)(ofp + 4);
    const float4 ofC = *(const float4*)(ofp + 8);
    const float4 ofD = *(const float4*)(ofp + 12);
    const float4 ofE = *(const float4*)(ofp + 16);
#define OFFSEL(idx) ((idx) < 4 ? f4get(ofA, (idx)) : (idx) < 8 ? f4get(ofB, (idx)-4) : \
                     (idx) < 12 ? f4get(ofC, (idx)-8) : (idx) < 16 ? f4get(ofD, (idx)-12) : f4get(ofE, (idx)-16))

    f32x4 acc[4];
    acc[0] = (f32x4){0.f, 0.f, 0.f, 0.f};
    acc[1] = acc[0]; acc[2] = acc[0]; acc[3] = acc[0];

#pragma unroll
    for (int kt = 0; kt < 9; ++kt) {
        float px_f = (float)(i + kt / 3) + OFFSEL(kt);
        float py_f = (float)(j + kt % 3) + OFFSEL(9 + kt);
        float qx = floorf(px_f), qy = floorf(py_f);
        int ltx = min(max((int)qx, 0), H - 1);
        int lty = min(max((int)qy, 0), W - 1);
        int rbx = min(max((int)qx + 1, 0), H - 1);
        int rby = min(max((int)qy + 1, 0), W - 1);
        float cpx = fminf(fmaxf(px_f, 0.0f), (float)(H - 1));
        float cpy = fminf(fmaxf(py_f, 0.0f), (float)(W - 1));
        float alt = 1.0f + ((float)ltx - cpx);
        float arb = 1.0f - ((float)rbx - cpx);
        float blt = 1.0f + ((float)lty - cpy);
        float brb = 1.0f - ((float)rby - cpy);
        float g0 = alt * blt, g1 = arb * brb, g2 = alt * brb, g3 = arb * blt;
        int slr = ltx - (i0 - 1), srr = rbx - (i0 - 1);
        int slc = lty - (j0 - 1), src = rby - (j0 - 1);
        const bool inp = ((unsigned)slr < (unsigned)PRW) & ((unsigned)srr < (unsigned)PRW) &
                         ((unsigned)slc < (unsigned)PCW) & ((unsigned)src < (unsigned)PCW);
#pragma unroll
        for (int chunk = 0; chunk < 2; ++chunk) {
            const int ch = chunk * 32 + quad * 8;
            float s[8];
#pragma unroll
            for (int hf = 0; hf < 2; ++hf) {
                const int cho = ch + hf * 4;
                float4 v0, v1, v2, v3;
                if (inp) {
                    v0 = *(const float4*)&Xs[(slr * PCW + slc) * XROW + cho];
                    v1 = *(const float4*)&Xs[(srr * PCW + src) * XROW + cho];
                    v2 = *(const float4*)&Xs[(slr * PCW + src) * XROW + cho];
                    v3 = *(const float4*)&Xs[(srr * PCW + slc) * XROW + cho];
                } else {
                    v0 = *(const float4*)(xb + (size_t)(ltx * W + lty) * 64 + cho);
                    v1 = *(const float4*)(xb + (size_t)(rbx * W + rby) * 64 + cho);
                    v2 = *(const float4*)(xb + (size_t)(ltx * W + rby) * 64 + cho);
                    v3 = *(const float4*)(xb + (size_t)(rbx * W + lty) * 64 + cho);
                }
                s[hf * 4 + 0] = g0 * v0.x + g1 * v1.x + g2 * v2.x + g3 * v3.x;
                s[hf * 4 + 1] = g0 * v0.y + g1 * v1.y + g2 * v2.y + g3 * v3.y;
                s[hf * 4 + 2] = g0 * v0.z + g1 * v1.z + g2 * v2.z + g3 * v3.z;
                s[hf * 4 + 3] = g0 * v0.w + g1 * v1.w + g2 * v2.w + g3 * v3.w;
            }
            if (LO) {
                bf16x8 afh, afl;
                split_bf8(s[0], s[1], s[2], s[3], s[4], s[5], s[6], s[7], afh, afl);
#pragma unroll
                for (int nt = 0; nt < 4; ++nt) {
                    const int fb = ((chunk * 9 + kt) * 4 + nt) * 512 + lane * 8;
                    bf16x8 bfh = *(const bf16x8*)(Wtdh + fb);
                    bf16x8 bfl = *(const bf16x8*)(Wtdl + fb);
                    acc[nt] = __builtin_amdgcn_mfma_f32_16x16x32_bf16(afh, bfh, acc[nt], 0, 0, 0);
                    acc[nt] = __builtin_amdgcn_mfma_f32_16x16x32_bf16(afl, bfh, acc[nt], 0, 0, 0);
                    acc[nt] = __builtin_amdgcn_mfma_f32_16x16x32_bf16(afh, bfl, acc[nt], 0, 0, 0);
                }
            } else {
                bf16x8 afh = cvt8hi(s);
#pragma unroll
                for (int nt = 0; nt < 4; ++nt) {
                    const int fb = ((chunk * 9 + kt) * 4 + nt) * 512 + lane * 8;
                    bf16x8 bfh = *(const bf16x8*)(Wtdh + fb);
                    acc[nt] = __builtin_amdgcn_mfma_f32_16x16x32_bf16(afh, bfh, acc[nt], 0, 0, 0);
                }
            }
        }
    }
#undef OFFSEL

    // ============ EPILOGUE: store + fused stats (Ld reuses Xs) ============
    __syncthreads();                          // all Xs reads done before overwrite
    float* Ld = Xs;
    const int pr0 = wv * 16 + quad * 4;
    if (OUT_NHWC) {
#pragma unroll
        for (int nt = 0; nt < 4; ++nt) {
            int c = nt * 16 + l15;
#pragma unroll
            for (int r = 0; r < 4; ++r)
                Ld[(pr0 + r) * LDROW + c] = acc[nt][r];
        }
        __syncthreads();
#pragma unroll
        for (int it = 0; it < 4; ++it) {      // 1024 f4 = 64px x 16 groups
            int idx = it * 256 + t;
            int px = idx >> 4, c4 = idx & 15;
            float4 v = *(float4*)&Ld[px * LDROW + c4 * 4];
            int pij = (i0 + (px >> 3)) * W + j0 + (px & 7);
            *(float4*)(out + (size_t)(b * HW + pij) * 64 + c4 * 4) = v;
        }
    } else {
#pragma unroll
        for (int nt = 0; nt < 4; ++nt) {
            int c = nt * 16 + l15;
#pragma unroll
            for (int r = 0; r < 4; ++r)
                Ld[c * LDROW + pr0 + r] = acc[nt][r];
        }
        __syncthreads();
#pragma unroll
        for (int it = 0; it < 4; ++it) {      // 1024 f4 = 64ch x 16 groups
            int idx = it * 256 + t;
            int c = idx >> 4, p4 = idx & 15;
            float4 v = *(float4*)&Ld[c * LDROW + p4 * 4];
            int pij = (i0 + (p4 >> 1)) * W + j0 + (p4 & 1) * 4;
            *(float4*)(out + (size_t)(b * COUT + c) * HW + pij) = v;
        }
    }
    {
        float* Sr = offL;                     // offsets dead; 2KB needed
        int c = t & 63, g = t >> 6;
        float s = 0.f, q = 0.f;
        if (OUT_NHWC) {
#pragma unroll
            for (int k = 0; k < 16; ++k) {
                float v = Ld[(g * 16 + k) * LDROW + c];
                s += v; q += v * v;
            }
        } else {
#pragma unroll
            for (int k4 = 0; k4 < 4; ++k4) {
                float4 v = *(const float4*)&Ld[c * LDROW + g * 16 + k4 * 4];
                s += v.x + v.y + v.z + v.w;
                q += v.x * v.x + v.y * v.y + v.z * v.z + v.w * v.w;
            }
        }
        Sr[g * 64 + c]       = s;
        Sr[256 + g * 64 + c] = q;
        __syncthreads();
        if (t < 64) {
            float ts = Sr[t] + Sr[64 + t] + Sr[128 + t] + Sr[192 + t];
            float tq = Sr[256 + t] + Sr[320 + t] + Sr[384 + t] + Sr[448 + t];
            atomicAdd(&acc_g[t], ts);         // (was: part[blk*128+t] = ts)
            atomicAdd(&acc_g[64 + t], tq);
        }
    }
}

// ---------------------------------------------------------------------------
// BN+ReLU on NHWC (stage 1). scale/shift computed inline from atomics
// (replaces k_stats2; ~10 L1-hot ops per thread).
// ---------------------------------------------------------------------------
__global__ __launch_bounds__(256) void k_bnrelu_nhwc(const float* __restrict__ y,
                                                     const float* __restrict__ acc,
                                                     const float* __restrict__ gamma,
                                                     const float* __restrict__ beta,
                                                     float* __restrict__ out) {
    size_t idx = ((size_t)blockIdx.x * 256 + threadIdx.x) * 4;
    int c4 = (int)(idx & 63);
    float4 sc, sh;
    bn_coef(acc, gamma, beta, c4 + 0, sc.x, sh.x);
    bn_coef(acc, gamma, beta, c4 + 1, sc.y, sh.y);
    bn_coef(acc, gamma, beta, c4 + 2, sc.z, sh.z);
    bn_coef(acc, gamma, beta, c4 + 3, sc.w, sh.w);
    float4 v = *(const float4*)(y + idx);
    float4 r;
    r.x = fmaxf(fmaf(v.x, sc.x, sh.x), 0.f);
    r.y = fmaxf(fmaf(v.y, sc.y, sh.y), 0.f);
    r.z = fmaxf(fmaf(v.z, sc.z, sh.z), 0.f);
    r.w = fmaxf(fmaf(v.w, sc.w, sh.w), 0.f);
    *(float4*)(out + idx) = r;
}

// ---------------------------------------------------------------------------
// BN+ReLU on NCHW, IN-PLACE (stage 2). scale/shift inline from atomics.
// ---------------------------------------------------------------------------
__global__ __launch_bounds__(256) void k_bnrelu_nchw(float* __restrict__ y,
                                                     const float* __restrict__ acc,
                                                     const float* __restrict__ gamma,
                                                     const float* __restrict__ beta) {
    int c = (blockIdx.x / 49) % COUT;
    float scale, shift;
    bn_coef(acc, gamma, beta, c, scale, shift);
    size_t idx = ((size_t)blockIdx.x * 1024) + threadIdx.x * 4;
    float4 v = *(const float4*)(y + idx);
    float4 r;
    r.x = fmaxf(fmaf(v.x, scale, shift), 0.f);
    r.y = fmaxf(fmaf(v.y, scale, shift), 0.f);
    r.z = fmaxf(fmaf(v.z, scale, shift), 0.f);
    r.w = fmaxf(fmaf(v.w, scale, shift), 0.f);
    *(float4*)(y + idx) = r;
}

// ---------------------------------------------------------------------------
// Flow (5 kernel launches + 1 memset):
//   0 memset acc1/acc2 (1 KB)
//   1 k_prep_all:  x -> bufB (xT), both stages' weights
//   2 k_fused<NHWC,LO>: bufB -> out (y1 raw NHWC), atomics -> acc1
//   3 k_bnrelu_nhwc: out -> bufB (BN1 from acc1)
//   4 k_fused<NCHW,hi>: bufB -> out (y2 raw NCHW), atomics -> acc2
//   5 k_bnrelu_nchw: out in-place (BN2 from acc2)
// Workspace (~27 MB): weights 432 KB | acc 1 KB | bufB 25.7 MB.
// ---------------------------------------------------------------------------
extern "C" void kernel_launch(void* const* d_in, const int* in_sizes, int n_in,
                              void* d_out, int out_size, void* d_ws, size_t ws_size,
                              hipStream_t stream) {
    const float* x       = (const float*)d_in[0];
    const float* w_off1  = (const float*)d_in[1];
    const float* b_off1  = (const float*)d_in[2];
    const float* w_conv1 = (const float*)d_in[3];
    const float* gamma1  = (const float*)d_in[4];
    const float* beta1   = (const float*)d_in[5];
    const float* w_off2  = (const float*)d_in[6];
    const float* b_off2  = (const float*)d_in[7];
    const float* w_conv2 = (const float*)d_in[8];
    const float* gamma2  = (const float*)d_in[9];
    const float* beta2   = (const float*)d_in[10];
    float* out = (float*)d_out;

    char*  wsb   = (char*)d_ws;
    short* Wtd1h = (short*)wsb;                          // 73728
    short* Wtd1l = (short*)(wsb + 73728);                // 73728
    short* Wto1h = (short*)(wsb + 147456);               // 36864
    short* Wto1l = (short*)(wsb + 184320);               // 36864
    short* Wtd2h = (short*)(wsb + 221184);               // 73728
    short* Wtd2l = (short*)(wsb + 294912);               // 73728
    short* Wto2h = (short*)(wsb + 368640);               // 36864
    short* Wto2l = (short*)(wsb + 405504);               // 36864
    float* acc1  = (float*)(wsb + 442368);               // 512 B (128 f32)
    float* acc2  = (float*)(wsb + 442880);               // 512 B
    float* bufB  = (float*)(wsb + 1245696);              // xT/y1: 25690112

    const int bn_blocks = (BATCH * COUT * HW) / 1024;    // 6272

    // zero the stats accumulators (stream-ordered, graph-capturable)
    hipMemsetAsync(wsb + 442368, 0, 1024, stream);

    // ---- front: transpose + both weight preps in ONE launch ----
    k_prep_all    <<<TPB + 216, 256, 0, stream>>>(x, bufB, w_conv1, w_off1,
                                                  w_conv2, w_off2,
                                                  Wtd1h, Wtd1l, Wto1h, Wto1l,
                                                  Wtd2h, Wtd2l, Wto2h, Wto2l);

    // ---- stage 1 (full hi/lo deform; y1 raw -> out; stats -> acc1) ----
    k_fused<true, true> <<<NBLK, 256, 0, stream>>>(bufB, Wto1h, Wto1l, b_off1,
                                                   Wtd1h, Wtd1l, out, acc1);
    k_bnrelu_nhwc <<<bn_blocks, 256, 0, stream>>>(out, acc1, gamma1, beta1, bufB);

    // ---- stage 2 (hi-only deform; y2 raw -> out; stats -> acc2) ----
    k_fused<false, false><<<NBLK, 256, 0, stream>>>(bufB, Wto2h, Wto2l, b_off2,
                                                    Wtd2h, Wtd2l, out, acc2);
    k_bnrelu_nchw <<<bn_blocks, 256, 0, stream>>>(out, acc2, gamma2, beta2);
}

// Round 10
// 286.980 us; speedup vs baseline: 1.0436x; 1.0436x over previous
//
#include <hip/hip_runtime.h>

#define H 224
#define W 224
#define HW (H*W)
#define BATCH 2
#define CIN 64
#define COUT 64
#define NOFF 18
#define K576 576          // K = 64 ch * 9 taps
#define OFFS 20           // off LDS stride (18 live, f4-aligned)
#define NBLK (BATCH*HW/64)          // 1568 tiles (8x8 pixels)
#define NB8  (NBLK/8)               // 196 blocks per XCD span
#define TC8  28                     // 224/8 tiles per image row/col
#define XROW 68                     // staged patch ch-stride (64 + 4 pad)
#define PRW 10                      // patch rows (8 + 2 halo)
#define PCW 10                      // patch cols
#define LDROW 72                    // epilogue staging stride
#define TPB  (BATCH*HW/64)          // transpose blocks = 1568
#define NCOPY 16                    // stats accumulator copies (de-contend)

typedef __attribute__((ext_vector_type(8))) short bf16x8;
typedef __attribute__((ext_vector_type(4))) short s16x4;
typedef __attribute__((ext_vector_type(4))) float f32x4;

__device__ inline short f2bf(float f) {
    unsigned u = __float_as_uint(f);
    u += 0x7FFF + ((u >> 16) & 1);
    return (short)(u >> 16);
}
__device__ inline float bf2f(short h) {
    return __uint_as_float(((unsigned)(unsigned short)h) << 16);
}
__device__ inline void split_bf(float x, short& hi, short& lo) {
    hi = f2bf(x);
    lo = f2bf(x - bf2f(hi));
}
__device__ inline void split_bf4(float a, float b, float c, float d,
                                 s16x4& h4, s16x4& l4) {
    short h0, l0, h1, l1, h2, l2, h3, l3;
    split_bf(a, h0, l0); split_bf(b, h1, l1);
    split_bf(c, h2, l2); split_bf(d, h3, l3);
    h4 = (s16x4){h0, h1, h2, h3};
    l4 = (s16x4){l0, l1, l2, l3};
}
__device__ inline void split_bf8(float a0, float a1, float a2, float a3,
                                 float a4, float a5, float a6, float a7,
                                 bf16x8& hi, bf16x8& lo) {
    s16x4 h0, l0, h1, l1;
    split_bf4(a0, a1, a2, a3, h0, l0);
    split_bf4(a4, a5, a6, a7, h1, l1);
    hi = __builtin_shufflevector(h0, h1, 0, 1, 2, 3, 4, 5, 6, 7);
    lo = __builtin_shufflevector(l0, l1, 0, 1, 2, 3, 4, 5, 6, 7);
}
__device__ inline bf16x8 cvt8hi(const float* s) {
    return (bf16x8){f2bf(s[0]), f2bf(s[1]), f2bf(s[2]), f2bf(s[3]),
                    f2bf(s[4]), f2bf(s[5]), f2bf(s[6]), f2bf(s[7])};
}
__device__ inline int swizzle_blk(int raw) {
    return (raw & 7) * NB8 + (raw >> 3);
}
__device__ __forceinline__ float f4get(float4 v, int k) {
    switch (k & 3) { case 0: return v.x; case 1: return v.y; case 2: return v.z; default: return v.w; }
}

// ---------------------------------------------------------------------------
// Combined front kernel: blocks [0,TPB) transpose x NCHW->NHWC; blocks
// [TPB, TPB+216) prep BOTH stages' weights (wave-contiguous fragment layout):
// Deform:  Wd[((chunk*9+kt)*4+nt)*512 + lane*8 + e]
//   n = nt*16 + (lane&15); c = chunk*32 + (lane>>4)*8 + e; tap = kt
// Offconv: Wo[((chunk*9+kt)*2+ntb)*512 + lane*8 + e]   (n>=18 rows zero)
// ---------------------------------------------------------------------------
__global__ __launch_bounds__(256) void k_prep_all(const float* __restrict__ x,
                                                  float* __restrict__ xT,
                                                  const float* __restrict__ wconv1,
                                                  const float* __restrict__ woff1,
                                                  const float* __restrict__ wconv2,
                                                  const float* __restrict__ woff2,
                                                  short* __restrict__ Wtd1h,
                                                  short* __restrict__ Wtd1l,
                                                  short* __restrict__ Wto1h,
                                                  short* __restrict__ Wto1l,
                                                  short* __restrict__ Wtd2h,
                                                  short* __restrict__ Wtd2l,
                                                  short* __restrict__ Wto2h,
                                                  short* __restrict__ Wto2l) {
    __shared__ float Lt[64][65];
    if (blockIdx.x < TPB) {
        // ---- NCHW -> NHWC transpose (identical to R1 k_transpose) ----
        int blk = blockIdx.x, t = threadIdx.x;
        int px0 = blk * 64;
        int b   = px0 / HW;
        int ij0 = px0 - b * HW;
        int lane = t & 63, g = t >> 6;
#pragma unroll
        for (int r = 0; r < 16; ++r) {
            int c = r * 4 + g;
            Lt[c][lane] = x[(b * CIN + c) * HW + ij0 + lane];
        }
        __syncthreads();
#pragma unroll
        for (int r = 0; r < 16; ++r) {
            int px = r * 4 + g;
            xT[((size_t)(b * HW + ij0 + px)) * 64 + lane] = Lt[lane][px];
        }
        return;
    }
    // ---- weight prep, both stages ----
    int t = (blockIdx.x - TPB) * 256 + threadIdx.x;
    if (t < COUT * K576) {
        int e = t & 7, lane = (t >> 3) & 63, rest = t >> 9;
        int nt = rest & 3, kt9 = rest >> 2;
        int kt = kt9 % 9, chunk = kt9 / 9;
        int n = nt * 16 + (lane & 15);
        int c = chunk * 32 + (lane >> 4) * 8 + e;
        short h, l;
        split_bf(wconv1[n * K576 + c * 9 + kt], h, l);
        Wtd1h[t] = h; Wtd1l[t] = l;
        split_bf(wconv2[n * K576 + c * 9 + kt], h, l);
        Wtd2h[t] = h; Wtd2l[t] = l;
    }
    int t2 = t - COUT * K576;
    if (t2 >= 0 && t2 < 32 * K576) {
        int e = t2 & 7, lane = (t2 >> 3) & 63, rest = t2 >> 9;
        int ntb = rest & 1, kt9 = rest >> 1;
        int kt = kt9 % 9, chunk = kt9 / 9;
        int n = ntb * 16 + (lane & 15);
        int c = chunk * 32 + (lane >> 4) * 8 + e;
        short h, l;
        float v1 = (n < NOFF) ? woff1[n * K576 + c * 9 + kt] : 0.0f;
        split_bf(v1, h, l);
        Wto1h[t2] = h; Wto1l[t2] = l;
        float v2 = (n < NOFF) ? woff2[n * K576 + c * 9 + kt] : 0.0f;
        split_bf(v2, h, l);
        Wto2h[t2] = h; Wto2l[t2] = l;
    }
}

// ---------------------------------------------------------------------------
// FUSED, wave-autonomous — R6 core (passed, 289 us, absmax 0.125).
// Tail: per-block (sum,sumsq) -> atomics into acc copy (blockIdx & 15).
// R9 post-mortem: a SINGLE 512B accumulator serialized ~200K same-line
// atomics -> +8.5us/dispatch pure stall (MFMA/VALU cycle totals unchanged).
// 16 copies cut per-address traffic 1568 -> 98 and give each block private
// cachelines.
//   LO=true  (stage 1): full 3-term hi/lo bf16 deform product (y1 feeds
//     stage-2's offset conv -> floor(); R2 post-mortem).
//   LO=false (stage 2): hi*hi only deform (error ~0.06 << 0.795 threshold).
// NOTE: BN-at-load fusion (BN_IN) is PERMANENTLY BANNED — failed correctness
// three times (R2 3.4, R3 2.9, R7 1.156 scalar-only) with no mechanism found.
// ---------------------------------------------------------------------------
template <bool OUT_NHWC, bool LO>
__global__ __launch_bounds__(256, 4) void k_fused(const float* __restrict__ xT,
                                                  const short* __restrict__ Wtoh,
                                                  const short* __restrict__ Wtol,
                                                  const float* __restrict__ boff,
                                                  const short* __restrict__ Wtdh,
                                                  const short* __restrict__ Wtdl,
                                                  float* __restrict__ out,
                                                  float* __restrict__ acc_g) {
    // LDS: Xs 27200 | offL 5120 = 32320 B. Ld (18432) + Sr (2048) reuse them.
    __shared__ __align__(16) char smem[PRW * PCW * XROW * 4 + 64 * OFFS * 4];
    float* Xs   = (float*)smem;
    float* offL = (float*)(smem + PRW * PCW * XROW * 4);

    const int t    = threadIdx.x;
    const int lane = t & 63;
    const int wv   = t >> 6;
    const int l15  = lane & 15;
    const int quad = lane >> 4;
    const int vb   = swizzle_blk(blockIdx.x);
    const int b    = vb / (TC8 * TC8);
    const int rem  = vb - b * (TC8 * TC8);
    const int i0   = (rem / TC8) * 8;
    const int j0   = (rem % TC8) * 8;
    const int lp   = wv * 16 + l15;          // this lane's pixel 0..63
    const int i    = i0 + (lp >> 3);
    const int j    = j0 + (lp & 7);

    const float* xb = xT + (size_t)(b * HW) * 64;

    // ---- stage 10x10x64ch patch (border-clamped), shared by both phases ----
#pragma unroll
    for (int k = 0; k < 7; ++k) {
        int idx = k * 256 + t;               // 1600 = 100 slots x 16 f4
        if (idx < PRW * PCW * 16) {
            int slot = idx >> 4, e = idx & 15;
            int sr = slot / PCW, sc = slot - sr * PCW;
            int rr = min(max(i0 - 1 + sr, 0), H - 1);
            int cc = min(max(j0 - 1 + sc, 0), W - 1);
            *(float4*)&Xs[slot * XROW + e * 4] =
                *(const float4*)(xb + (size_t)(rr * W + cc) * 64 + e * 4);
        }
    }
    __syncthreads();

    // ============ PHASE 1: offset conv (zero-pad via mask), per-wave ============
    f32x4 aoc0 = (f32x4){0.f, 0.f, 0.f, 0.f};
    f32x4 aoc1 = (f32x4){0.f, 0.f, 0.f, 0.f};
#pragma unroll
    for (int kt = 0; kt < 9; ++kt) {
        const int di = kt / 3, dj = kt % 3;
        const int ii = i + di - 1, jj = j + dj - 1;
        const bool ok = (ii >= 0) && (ii < H) && (jj >= 0) && (jj < W);
        const float* xp = &Xs[(((lp >> 3) + di) * PCW + (lp & 7) + dj) * XROW + quad * 8];
#pragma unroll
        for (int chunk = 0; chunk < 2; ++chunk) {
            float4 va = make_float4(0.f, 0.f, 0.f, 0.f), vb4 = va;
            if (ok) {
                va  = *(const float4*)(xp + chunk * 32);
                vb4 = *(const float4*)(xp + chunk * 32 + 4);
            }
            bf16x8 afh, afl;
            split_bf8(va.x, va.y, va.z, va.w, vb4.x, vb4.y, vb4.z, vb4.w, afh, afl);
            const int fb = (chunk * 9 + kt) * 2 * 512 + lane * 8;
            bf16x8 bh0 = *(const bf16x8*)(Wtoh + fb);
            bf16x8 bl0 = *(const bf16x8*)(Wtol + fb);
            aoc0 = __builtin_amdgcn_mfma_f32_16x16x32_bf16(afh, bh0, aoc0, 0, 0, 0);
            aoc0 = __builtin_amdgcn_mfma_f32_16x16x32_bf16(afl, bh0, aoc0, 0, 0, 0);
            aoc0 = __builtin_amdgcn_mfma_f32_16x16x32_bf16(afh, bl0, aoc0, 0, 0, 0);
            bf16x8 bh1 = *(const bf16x8*)(Wtoh + fb + 512);
            bf16x8 bl1 = *(const bf16x8*)(Wtol + fb + 512);
            aoc1 = __builtin_amdgcn_mfma_f32_16x16x32_bf16(afh, bh1, aoc1, 0, 0, 0);
            aoc1 = __builtin_amdgcn_mfma_f32_16x16x32_bf16(afl, bh1, aoc1, 0, 0, 0);
            aoc1 = __builtin_amdgcn_mfma_f32_16x16x32_bf16(afh, bl1, aoc1, 0, 0, 0);
        }
    }
    // redistribute offsets: C layout holds [px=quad*4+r][n=l15(+16)] -> offL
    {
        const int pr0 = wv * 16 + quad * 4;
        const float bi = boff[l15];
#pragma unroll
        for (int r = 0; r < 4; ++r)
            offL[(pr0 + r) * OFFS + l15] = aoc0[r] + bi;
        if (l15 < 2) {
            const float bi2 = boff[16 + l15];
#pragma unroll
            for (int r = 0; r < 4; ++r)
                offL[(pr0 + r) * OFFS + 16 + l15] = aoc1[r] + bi2;
        }
    }
    __syncthreads();

    // ============ PHASE 2: deformable sampling + conv, per-wave ============
    const float* ofp = &offL[(wv * 16 + l15) * OFFS];
    const float4 ofA = *(const float4*)(ofp + 0);
    const float4 ofB = *(const float4*)(ofp + 4);
    const float4 ofC = *(const float4*)(ofp + 8);
    const float4 ofD = *(const float4*)(ofp + 12);
    const float4 ofE = *(const float4*)(ofp + 16);
#define OFFSEL(idx) ((idx) < 4 ? f4get(ofA, (idx)) : (idx) < 8 ? f4get(ofB, (idx)-4) : \
                     (idx) < 12 ? f4get(ofC, (idx)-8) : (idx) < 16 ? f4get(ofD, (idx)-12) : f4get(ofE, (idx)-16))

    f32x4 acc[4];
    acc[0] = (f32x4){0.f, 0.f, 0.f, 0.f};
    acc[1] = acc[0]; acc[2] = acc[0]; acc[3] = acc[0];

#pragma unroll
    for (int kt = 0; kt < 9; ++kt) {
        float px_f = (float)(i + kt / 3) + OFFSEL(kt);
        float py_f = (float)(j + kt % 3) + OFFSEL(9 + kt);
        float qx = floorf(px_f), qy = floorf(py_f);
        int ltx = min(max((int)qx, 0), H - 1);
        int lty = min(max((int)qy, 0), W - 1);
        int rbx = min(max((int)qx + 1, 0), H - 1);
        int rby = min(max((int)qy + 1, 0), W - 1);
        float cpx = fminf(fmaxf(px_f, 0.0f), (float)(H - 1));
        float cpy = fminf(fmaxf(py_f, 0.0f), (float)(W - 1));
        float alt = 1.0f + ((float)ltx - cpx);
        float arb = 1.0f - ((float)rbx - cpx);
        float blt = 1.0f + ((float)lty - cpy);
        float brb = 1.0f - ((float)rby - cpy);
        float g0 = alt * blt, g1 = arb * brb, g2 = alt * brb, g3 = arb * blt;
        int slr = ltx - (i0 - 1), srr = rbx - (i0 - 1);
        int slc = lty - (j0 - 1), src = rby - (j0 - 1);
        const bool inp = ((unsigned)slr < (unsigned)PRW) & ((unsigned)srr < (unsigned)PRW) &
                         ((unsigned)slc < (unsigned)PCW) & ((unsigned)src < (unsigned)PCW);
#pragma unroll
        for (int chunk = 0; chunk < 2; ++chunk) {
            const int ch = chunk * 32 + quad * 8;
            float s[8];
#pragma unroll
            for (int hf = 0; hf < 2; ++hf) {
                const int cho = ch + hf * 4;
                float4 v0, v1, v2, v3;
                if (inp) {
                    v0 = *(const float4*)&Xs[(slr * PCW + slc) * XROW + cho];
                    v1 = *(const float4*)&Xs[(srr * PCW + src) * XROW + cho];
                    v2 = *(const float4*)&Xs[(slr * PCW + src) * XROW + cho];
                    v3 = *(const float4*)&Xs[(srr * PCW + slc) * XROW + cho];
                } else {
                    v0 = *(const float4*)(xb + (size_t)(ltx * W + lty) * 64 + cho);
                    v1 = *(const float4*)(xb + (size_t)(rbx * W + rby) * 64 + cho);
                    v2 = *(const float4*)(xb + (size_t)(ltx * W + rby) * 64 + cho);
                    v3 = *(const float4*)(xb + (size_t)(rbx * W + lty) * 64 + cho);
                }
                s[hf * 4 + 0] = g0 * v0.x + g1 * v1.x + g2 * v2.x + g3 * v3.x;
                s[hf * 4 + 1] = g0 * v0.y + g1 * v1.y + g2 * v2.y + g3 * v3.y;
                s[hf * 4 + 2] = g0 * v0.z + g1 * v1.z + g2 * v2.z + g3 * v3.z;
                s[hf * 4 + 3] = g0 * v0.w + g1 * v1.w + g2 * v2.w + g3 * v3.w;
            }
            if (LO) {
                bf16x8 afh, afl;
                split_bf8(s[0], s[1], s[2], s[3], s[4], s[5], s[6], s[7], afh, afl);
#pragma unroll
                for (int nt = 0; nt < 4; ++nt) {
                    const int fb = ((chunk * 9 + kt) * 4 + nt) * 512 + lane * 8;
                    bf16x8 bfh = *(const bf16x8*)(Wtdh + fb);
                    bf16x8 bfl = *(const bf16x8*)(Wtdl + fb);
                    acc[nt] = __builtin_amdgcn_mfma_f32_16x16x32_bf16(afh, bfh, acc[nt], 0, 0, 0);
                    acc[nt] = __builtin_amdgcn_mfma_f32_16x16x32_bf16(afl, bfh, acc[nt], 0, 0, 0);
                    acc[nt] = __builtin_amdgcn_mfma_f32_16x16x32_bf16(afh, bfl, acc[nt], 0, 0, 0);
                }
            } else {
                bf16x8 afh = cvt8hi(s);
#pragma unroll
                for (int nt = 0; nt < 4; ++nt) {
                    const int fb = ((chunk * 9 + kt) * 4 + nt) * 512 + lane * 8;
                    bf16x8 bfh = *(const bf16x8*)(Wtdh + fb);
                    acc[nt] = __builtin_amdgcn_mfma_f32_16x16x32_bf16(afh, bfh, acc[nt], 0, 0, 0);
                }
            }
        }
    }
#undef OFFSEL

    // ============ EPILOGUE: store + fused stats (Ld reuses Xs) ============
    __syncthreads();                          // all Xs reads done before overwrite
    float* Ld = Xs;
    const int pr0 = wv * 16 + quad * 4;
    if (OUT_NHWC) {
#pragma unroll
        for (int nt = 0; nt < 4; ++nt) {
            int c = nt * 16 + l15;
#pragma unroll
            for (int r = 0; r < 4; ++r)
                Ld[(pr0 + r) * LDROW + c] = acc[nt][r];
        }
        __syncthreads();
#pragma unroll
        for (int it = 0; it < 4; ++it) {      // 1024 f4 = 64px x 16 groups
            int idx = it * 256 + t;
            int px = idx >> 4, c4 = idx & 15;
            float4 v = *(float4*)&Ld[px * LDROW + c4 * 4];
            int pij = (i0 + (px >> 3)) * W + j0 + (px & 7);
            *(float4*)(out + (size_t)(b * HW + pij) * 64 + c4 * 4) = v;
        }
    } else {
#pragma unroll
        for (int nt = 0; nt < 4; ++nt) {
            int c = nt * 16 + l15;
#pragma unroll
            for (int r = 0; r < 4; ++r)
                Ld[c * LDROW + pr0 + r] = acc[nt][r];
        }
        __syncthreads();
#pragma unroll
        for (int it = 0; it < 4; ++it) {      // 1024 f4 = 64ch x 16 groups
            int idx = it * 256 + t;
            int c = idx >> 4, p4 = idx & 15;
            float4 v = *(float4*)&Ld[c * LDROW + p4 * 4];
            int pij = (i0 + (p4 >> 1)) * W + j0 + (p4 & 1) * 4;
            *(float4*)(out + (size_t)(b * COUT + c) * HW + pij) = v;
        }
    }
    {
        float* Sr = offL;                     // offsets dead; 2KB needed
        int c = t & 63, g = t >> 6;
        float s = 0.f, q = 0.f;
        if (OUT_NHWC) {
#pragma unroll
            for (int k = 0; k < 16; ++k) {
                float v = Ld[(g * 16 + k) * LDROW + c];
                s += v; q += v * v;
            }
        } else {
#pragma unroll
            for (int k4 = 0; k4 < 4; ++k4) {
                float4 v = *(const float4*)&Ld[c * LDROW + g * 16 + k4 * 4];
                s += v.x + v.y + v.z + v.w;
                q += v.x * v.x + v.y * v.y + v.z * v.z + v.w * v.w;
            }
        }
        Sr[g * 64 + c]       = s;
        Sr[256 + g * 64 + c] = q;
        __syncthreads();
        if (t < 64) {
            float ts = Sr[t] + Sr[64 + t] + Sr[128 + t] + Sr[192 + t];
            float tq = Sr[256 + t] + Sr[320 + t] + Sr[384 + t] + Sr[448 + t];
            float* accp = acc_g + (blockIdx.x & (NCOPY - 1)) * 128;
            atomicAdd(&accp[t], ts);
            atomicAdd(&accp[64 + t], tq);
        }
    }
}

// ---------------------------------------------------------------------------
// BN+ReLU on NHWC (stage 1). 128-thread cooperative reduce of the 16 acc
// copies (2K floats, L2-hot) -> LDS coefs, then apply. Replaces k_stats2.
// ---------------------------------------------------------------------------
__global__ __launch_bounds__(256) void k_bnrelu_nhwc(const float* __restrict__ y,
                                                     const float* __restrict__ acc,
                                                     const float* __restrict__ gamma,
                                                     const float* __restrict__ beta,
                                                     float* __restrict__ out) {
    __shared__ float red[128], coef[128];
    int t = threadIdx.x;
    if (t < 128) {
        float s = 0.f;
#pragma unroll
        for (int cp = 0; cp < NCOPY; ++cp) s += acc[cp * 128 + t];
        red[t] = s;
    }
    __syncthreads();
    if (t < 64) {
        const float inv_m = 1.0f / (float)(BATCH * HW);
        float mu  = red[t] * inv_m;
        float var = red[64 + t] * inv_m - mu * mu;
        float sc  = rsqrtf(var + 1e-5f) * gamma[t];
        coef[t]      = sc;
        coef[64 + t] = beta[t] - mu * sc;
    }
    __syncthreads();
    size_t idx = ((size_t)blockIdx.x * 256 + t) * 4;
    int c4 = (int)(idx & 63);
    float4 sc = make_float4(coef[c4], coef[c4 + 1], coef[c4 + 2], coef[c4 + 3]);
    float4 sh = make_float4(coef[64 + c4], coef[64 + c4 + 1],
                            coef[64 + c4 + 2], coef[64 + c4 + 3]);
    float4 v = *(const float4*)(y + idx);
    float4 r;
    r.x = fmaxf(fmaf(v.x, sc.x, sh.x), 0.f);
    r.y = fmaxf(fmaf(v.y, sc.y, sh.y), 0.f);
    r.z = fmaxf(fmaf(v.z, sc.z, sh.z), 0.f);
    r.w = fmaxf(fmaf(v.w, sc.w, sh.w), 0.f);
    *(float4*)(out + idx) = r;
}

// ---------------------------------------------------------------------------
// BN+ReLU on NCHW, IN-PLACE (stage 2). One channel per block -> 32 uniform
// L2-hot loads reduce the copies, then apply.
// ---------------------------------------------------------------------------
__global__ __launch_bounds__(256) void k_bnrelu_nchw(float* __restrict__ y,
                                                     const float* __restrict__ acc,
                                                     const float* __restrict__ gamma,
                                                     const float* __restrict__ beta) {
    int c = (blockIdx.x / 49) % COUT;
    float s = 0.f, q = 0.f;
#pragma unroll
    for (int cp = 0; cp < NCOPY; ++cp) {
        s += acc[cp * 128 + c];
        q += acc[cp * 128 + 64 + c];
    }
    const float inv_m = 1.0f / (float)(BATCH * HW);
    float mu    = s * inv_m;
    float var   = q * inv_m - mu * mu;
    float scale = rsqrtf(var + 1e-5f) * gamma[c];
    float shift = beta[c] - mu * scale;
    size_t idx = ((size_t)blockIdx.x * 1024) + threadIdx.x * 4;
    float4 v = *(const float4*)(y + idx);
    float4 r;
    r.x = fmaxf(fmaf(v.x, scale, shift), 0.f);
    r.y = fmaxf(fmaf(v.y, scale, shift), 0.f);
    r.z = fmaxf(fmaf(v.z, scale, shift), 0.f);
    r.w = fmaxf(fmaf(v.w, scale, shift), 0.f);
    *(float4*)(y + idx) = r;
}

// ---------------------------------------------------------------------------
// Flow (5 kernel launches + 1 memset):
//   0 memset acc1/acc2 (16 KB)
//   1 k_prep_all:  x -> bufB (xT), both stages' weights
//   2 k_fused<NHWC,LO>: bufB -> out (y1 raw NHWC), atomics -> acc1[16][128]
//   3 k_bnrelu_nhwc: out -> bufB (BN1 reduced inline from acc1)
//   4 k_fused<NCHW,hi>: bufB -> out (y2 raw NCHW), atomics -> acc2[16][128]
//   5 k_bnrelu_nchw: out in-place (BN2 reduced inline from acc2)
// Workspace (~27 MB): weights 432 KB | acc 16 KB | bufB 25.7 MB.
// ---------------------------------------------------------------------------
extern "C" void kernel_launch(void* const* d_in, const int* in_sizes, int n_in,
                              void* d_out, int out_size, void* d_ws, size_t ws_size,
                              hipStream_t stream) {
    const float* x       = (const float*)d_in[0];
    const float* w_off1  = (const float*)d_in[1];
    const float* b_off1  = (const float*)d_in[2];
    const float* w_conv1 = (const float*)d_in[3];
    const float* gamma1  = (const float*)d_in[4];
    const float* beta1   = (const float*)d_in[5];
    const float* w_off2  = (const float*)d_in[6];
    const float* b_off2  = (const float*)d_in[7];
    const float* w_conv2 = (const float*)d_in[8];
    const float* gamma2  = (const float*)d_in[9];
    const float* beta2   = (const float*)d_in[10];
    float* out = (float*)d_out;

    char*  wsb   = (char*)d_ws;
    short* Wtd1h = (short*)wsb;                          // 73728
    short* Wtd1l = (short*)(wsb + 73728);                // 73728
    short* Wto1h = (short*)(wsb + 147456);               // 36864
    short* Wto1l = (short*)(wsb + 184320);               // 36864
    short* Wtd2h = (short*)(wsb + 221184);               // 73728
    short* Wtd2l = (short*)(wsb + 294912);               // 73728
    short* Wto2h = (short*)(wsb + 368640);               // 36864
    short* Wto2l = (short*)(wsb + 405504);               // 36864
    float* acc1  = (float*)(wsb + 442368);               // 16*128*4 = 8192
    float* acc2  = (float*)(wsb + 450560);               // 8192
    float* bufB  = (float*)(wsb + 1245696);              // xT/y1: 25690112

    const int bn_blocks = (BATCH * COUT * HW) / 1024;    // 6272

    // zero the stats accumulators (stream-ordered, graph-capturable)
    hipMemsetAsync(wsb + 442368, 0, 2 * NCOPY * 128 * 4, stream);

    // ---- front: transpose + both weight preps in ONE launch ----
    k_prep_all    <<<TPB + 216, 256, 0, stream>>>(x, bufB, w_conv1, w_off1,
                                                  w_conv2, w_off2,
                                                  Wtd1h, Wtd1l, Wto1h, Wto1l,
                                                  Wtd2h, Wtd2l, Wto2h, Wto2l);

    // ---- stage 1 (full hi/lo deform; y1 raw -> out; stats -> acc1) ----
    k_fused<true, true> <<<NBLK, 256, 0, stream>>>(bufB, Wto1h, Wto1l, b_off1,
                                                   Wtd1h, Wtd1l, out, acc1);
    k_bnrelu_nhwc <<<bn_blocks, 256, 0, stream>>>(out, acc1, gamma1, beta1, bufB);

    // ---- stage 2 (hi-only deform; y2 raw -> out; stats -> acc2) ----
    k_fused<false, false><<<NBLK, 256, 0, stream>>>(bufB, Wto2h, Wto2l, b_off2,
                                                    Wtd2h, Wtd2l, out, acc2);
    k_bnrelu_nchw <<<bn_blocks, 256, 0, stream>>>(out, acc2, gamma2, beta2);
}